// Round 2
// baseline (7298.369 us; speedup 1.0000x reference)
//
#include <hip/hip_runtime.h>
#include <math.h>

constexpr int CH   = 128;      // CH_IN == CH_LAT == CLASSES
constexpr int WW   = 131072;   // W
constexpr int NB   = 4;        // B
constexpr int NPIX = NB * WW;  // 524288
constexpr int TPB  = 256;

// ws float layout: [0,16384): w1t (transposed conv1_w, [c][o])
//                  [16384,16512): bnA (scale), [16512,16640): bnC (offset, b1 folded)
__global__ __launch_bounds__(256) void prep_kernel(
    const float* __restrict__ w1, const float* __restrict__ b1,
    const float* __restrict__ gamma, const float* __restrict__ beta,
    const float* __restrict__ mean, const float* __restrict__ var,
    float* __restrict__ ws)
{
    const int tid = threadIdx.x;
    for (int i = tid; i < CH * CH; i += 256) {
        const int o = i >> 7, c = i & 127;
        ws[c * CH + o] = w1[o * CH + c];
    }
    if (tid < CH) {
        const float s = gamma[tid] / sqrtf(var[tid] + 1e-5f);
        ws[16384 + tid] = s;
        ws[16512 + tid] = (b1[tid] - mean[tid]) * s + beta[tid];
    }
}

// Fully fused, LDS-free: weights/BN via wave-uniform (scalar) loads, x coalesced
// once, latent kept in 128 VGPR accumulators, argmax + gathers per-lane.
__global__ __launch_bounds__(TPB, 1) void fused_kernel(
    const float* __restrict__ x,     // (B,128,1,W)
    const float* __restrict__ w2,    // (129,128) row-major
    const float* __restrict__ b2,    // (129)
    const float* __restrict__ cmw,   // (128,128)
    const float* __restrict__ cmb,   // (128)
    const float* __restrict__ ws,    // prep output
    float* __restrict__ out)         // [0,NPIX): reg-out, [NPIX,2NPIX): mask
{
    const int tid = threadIdx.x;
    const int p   = blockIdx.x * TPB + tid;
    const int b   = p >> 17;          // / W  (uniform per block: 131072 % 256 == 0)
    const int w   = p & (WW - 1);

    const float* __restrict__ w1t = ws;
    const float* __restrict__ bnA = ws + 16384;
    const float* __restrict__ bnC = ws + 16512;

    // ---- GEMM1: acc[o] = sum_c x[b,c,w] * w1[o][c]  (c-outer, w1t uniform) ----
    float acc[CH];
    #pragma unroll
    for (int o = 0; o < CH; ++o) acc[o] = 0.f;

    const float* xc = x + ((size_t)b * CH) * WW + w;
    #pragma unroll 2
    for (int c = 0; c < CH; ++c) {
        const float xv = xc[(size_t)c * WW];          // coalesced, 1 load/lane/c
        const float* __restrict__ wr = w1t + c * CH;  // uniform -> s_load
        #pragma unroll
        for (int o = 0; o < CH; ++o)
            acc[o] = fmaf(xv, wr[o], acc[o]);
    }

    // ---- BN + LeakyReLU (b1 folded into bnC) ----
    #pragma unroll
    for (int o = 0; o < CH; ++o) {
        const float v = fmaf(acc[o], bnA[o], bnC[o]);
        acc[o] = (v >= 0.f) ? v : 0.01f * v;
    }

    // ---- GEMM2 rows 0..127 in groups of 8 + running argmax (strict >, in order) ----
    float best = -3.0e38f;
    int   bidx = 0;
    for (int rg = 0; rg < 16; ++rg) {
        float y[8];
        #pragma unroll
        for (int j = 0; j < 8; ++j) y[j] = b2[rg * 8 + j];   // uniform
        const float* __restrict__ w2b = w2 + rg * 8 * CH;
        #pragma unroll 4
        for (int c = 0; c < CH; ++c) {
            #pragma unroll
            for (int j = 0; j < 8; ++j)
                y[j] = fmaf(acc[c], w2b[j * CH + c], y[j]);  // uniform w2 reads
        }
        #pragma unroll
        for (int j = 0; j < 8; ++j) {
            const bool g = y[j] > best;
            best = g ? y[j] : best;
            bidx = g ? rg * 8 + j : bidx;
        }
    }

    // ---- mask row (w2 row 128) ----
    {
        const float* __restrict__ wm = w2 + CH * CH;         // uniform
        float m0 = 0.f, m1 = 0.f, m2 = 0.f, m3 = 0.f;
        #pragma unroll
        for (int i = 0; i < 32; ++i) {
            m0 = fmaf(acc[i*4+0], wm[i*4+0], m0);
            m1 = fmaf(acc[i*4+1], wm[i*4+1], m1);
            m2 = fmaf(acc[i*4+2], wm[i*4+2], m2);
            m3 = fmaf(acc[i*4+3], wm[i*4+3], m3);
        }
        const float mv   = ((m0 + m1) + (m2 + m3)) + b2[CH];
        out[NPIX + p]    = (mv >= 0.f) ? mv : 0.01f * mv;
    }

    // ---- cm gather (per-lane, L2) + reg dot ----
    {
        const float4* __restrict__ cr = (const float4*)(cmw + (size_t)bidx * CH);
        float r0 = 0.f, r1 = 0.f, r2 = 0.f, r3 = 0.f;
        #pragma unroll
        for (int i = 0; i < 32; ++i) {
            const float4 v = cr[i];
            r0 = fmaf(acc[i*4+0], v.x, r0);
            r1 = fmaf(acc[i*4+1], v.y, r1);
            r2 = fmaf(acc[i*4+2], v.z, r2);
            r3 = fmaf(acc[i*4+3], v.w, r3);
        }
        const float reg = ((r0 + r1) + (r2 + r3)) + cmb[bidx];
        out[p] = ((float)bidx + reg) * (1.0f / 128.0f);
    }
}

extern "C" void kernel_launch(void* const* d_in, const int* in_sizes, int n_in,
                              void* d_out, int out_size, void* d_ws, size_t ws_size,
                              hipStream_t stream) {
    const float* x     = (const float*)d_in[0];
    const float* w1    = (const float*)d_in[1];
    const float* b1    = (const float*)d_in[2];
    const float* gamma = (const float*)d_in[3];
    const float* beta  = (const float*)d_in[4];
    const float* mean  = (const float*)d_in[5];
    const float* var   = (const float*)d_in[6];
    const float* w2    = (const float*)d_in[7];
    const float* b2    = (const float*)d_in[8];
    const float* cmw   = (const float*)d_in[9];
    const float* cmb   = (const float*)d_in[10];
    float* ws  = (float*)d_ws;
    float* out = (float*)d_out;

    hipLaunchKernelGGL(prep_kernel, dim3(1), dim3(256), 0, stream,
                       w1, b1, gamma, beta, mean, var, ws);
    hipLaunchKernelGGL(fused_kernel, dim3(NPIX / TPB), dim3(TPB), 0, stream,
                       x, w2, b2, cmw, cmb, ws, out);
}

// Round 3
// 1656.703 us; speedup vs baseline: 4.4054x; 4.4054x over previous
//
#include <hip/hip_runtime.h>
#include <math.h>

constexpr int CH   = 128;      // CH_IN == CH_LAT == CLASSES
constexpr int WW   = 131072;   // W
constexpr int NB   = 4;        // B
constexpr int NPIX = NB * WW;  // 524288
constexpr int TPB  = 64;       // 1 wave/block; 32KB LDS/block -> ~5 blocks/CU

constexpr int W2S     = 132;   // padded row stride for w2t
constexpr int OFF_W1T = 0;              // w1t[c][o], 128*128
constexpr int OFF_BNA = 16384;          // BN scale, 128
constexpr int OFF_BNC = 16512;          // BN offset (b1 folded), 128
constexpr int OFF_W2T = 16640;          // w2t[c][j] stride 132 (j<129 valid, rest 0)

__global__ __launch_bounds__(256) void prep_kernel(
    const float* __restrict__ w1, const float* __restrict__ b1,
    const float* __restrict__ gamma, const float* __restrict__ beta,
    const float* __restrict__ mean, const float* __restrict__ var,
    const float* __restrict__ w2,
    float* __restrict__ ws)
{
    const int tid = threadIdx.x;
    for (int i = tid; i < CH * CH; i += 256) {
        const int c = i >> 7, o = i & 127;
        ws[OFF_W1T + c * CH + o] = w1[o * CH + c];
    }
    if (tid < CH) {
        const float s = gamma[tid] / sqrtf(var[tid] + 1e-5f);  // same math as passing rounds
        ws[OFF_BNA + tid] = s;
        ws[OFF_BNC + tid] = (b1[tid] - mean[tid]) * s + beta[tid];
    }
    for (int c = tid; c < CH; c += 256) {
        for (int j = 0; j < W2S; ++j)
            ws[OFF_W2T + c * W2S + j] = (j < CH + 1) ? w2[j * CH + c] : 0.f;
    }
}

// Phase 1: GEMM1 into static-indexed acc[128] (registers), uniform weights (SGPR).
// Phase 2: BN+LReLU, park latent in a PRIVATE LDS row (bank-rotated, no barriers).
// Phase 3: GEMM2 with static y[129] registers, latent read from LDS (runtime idx OK).
// Phase 4: argmax (static unroll), mask, cm gather + reg dot (round-1/2 association).
__global__ __launch_bounds__(TPB, 1) void fused_kernel(
    const float* __restrict__ x,     // (B,128,1,W)
    const float* __restrict__ b2,    // (129)
    const float* __restrict__ cmw,   // (128,128)
    const float* __restrict__ cmb,   // (128)
    const float* __restrict__ ws,
    float* __restrict__ out)         // [0,NPIX): reg-out, [NPIX,2NPIX): mask
{
    __shared__ float lat[TPB][CH];   // 32KB, thread-private rows

    const int tid = threadIdx.x;
    const int p   = blockIdx.x * TPB + tid;
    const int b   = p >> 17;                  // / W
    const int w   = p & (WW - 1);

    const float* __restrict__ w1t = ws + OFF_W1T;
    const float* __restrict__ bnA = ws + OFF_BNA;
    const float* __restrict__ bnC = ws + OFF_BNC;
    const float* __restrict__ w2t = ws + OFF_W2T;

    // ---- GEMM1: acc[o] = sum_c x[b,c,w] * w1[o][c] ----
    float acc[CH];
    #pragma unroll
    for (int o = 0; o < CH; ++o) acc[o] = 0.f;

    const float* xc = x + ((size_t)b * CH) * WW + w;
    #pragma unroll 2
    for (int c = 0; c < CH; ++c) {
        const float xv = xc[(size_t)c * WW];           // coalesced, 1 load/lane/c
        const float* __restrict__ wr = w1t + c * CH;   // wave-uniform -> s_load
        #pragma unroll
        for (int o = 0; o < CH; ++o)
            acc[o] = fmaf(xv, wr[o], acc[o]);          // acc index STATIC
    }

    // ---- BN + LeakyReLU, park latent in private LDS row (rotated: bank = (tid+o)%32) ----
    #pragma unroll
    for (int o = 0; o < CH; ++o) {
        float v = fmaf(acc[o], bnA[o], bnC[o]);        // identical association to R1/R2
        v = (v >= 0.f) ? v : 0.01f * v;
        lat[tid][(o + tid) & 127] = v;
    }
    // no __syncthreads: each thread only ever touches its own LDS row

    // ---- GEMM2: y[j] += lat[c] * w2[j][c], c ascending per accumulator (matches R1/R2) ----
    float y[CH + 1];
    #pragma unroll
    for (int j = 0; j <= CH; ++j) y[j] = b2[j];        // uniform -> s_load
    #pragma unroll 2
    for (int c = 0; c < CH; ++c) {
        const float a = lat[tid][(c + tid) & 127];     // runtime index into LDS: legal
        const float* __restrict__ wr = w2t + c * W2S;  // wave-uniform -> s_load
        #pragma unroll
        for (int j = 0; j <= CH; ++j)
            y[j] = fmaf(a, wr[j], y[j]);               // y index STATIC
    }

    // ---- argmax (strict >, ascending j => first-index tie-break) ----
    float best = y[0];
    int   bidx = 0;
    #pragma unroll
    for (int j = 1; j < CH; ++j) {
        const bool g = y[j] > best;
        best = g ? y[j] : best;
        bidx = g ? j : bidx;
    }

    // ---- mask (w2 row 128) ----
    const float mv = y[CH];
    out[NPIX + p]  = (mv >= 0.f) ? mv : 0.01f * mv;

    // ---- cm gather + reg dot (same 4-way split association as R1/R2) ----
    const float4* __restrict__ cr = (const float4*)(cmw + (size_t)bidx * CH);
    float r0 = 0.f, r1 = 0.f, r2 = 0.f, r3 = 0.f;
    #pragma unroll 4
    for (int c4 = 0; c4 < 32; ++c4) {
        const float4 v = cr[c4];
        r0 = fmaf(lat[tid][(4*c4 + 0 + tid) & 127], v.x, r0);
        r1 = fmaf(lat[tid][(4*c4 + 1 + tid) & 127], v.y, r1);
        r2 = fmaf(lat[tid][(4*c4 + 2 + tid) & 127], v.z, r2);
        r3 = fmaf(lat[tid][(4*c4 + 3 + tid) & 127], v.w, r3);
    }
    const float reg = ((r0 + r1) + (r2 + r3)) + cmb[bidx];
    out[p] = ((float)bidx + reg) * (1.0f / 128.0f);
}

extern "C" void kernel_launch(void* const* d_in, const int* in_sizes, int n_in,
                              void* d_out, int out_size, void* d_ws, size_t ws_size,
                              hipStream_t stream) {
    const float* x     = (const float*)d_in[0];
    const float* w1    = (const float*)d_in[1];
    const float* b1    = (const float*)d_in[2];
    const float* gamma = (const float*)d_in[3];
    const float* beta  = (const float*)d_in[4];
    const float* mean  = (const float*)d_in[5];
    const float* var   = (const float*)d_in[6];
    const float* w2    = (const float*)d_in[7];
    const float* b2    = (const float*)d_in[8];
    const float* cmw   = (const float*)d_in[9];
    const float* cmb   = (const float*)d_in[10];
    float* ws  = (float*)d_ws;
    float* out = (float*)d_out;

    hipLaunchKernelGGL(prep_kernel, dim3(1), dim3(256), 0, stream,
                       w1, b1, gamma, beta, mean, var, w2, ws);
    hipLaunchKernelGGL(fused_kernel, dim3(NPIX / TPB), dim3(TPB), 0, stream,
                       x, b2, cmw, cmb, ws, out);
}

// Round 4
// 1054.770 us; speedup vs baseline: 6.9194x; 1.5707x over previous
//
#include <hip/hip_runtime.h>
#include <math.h>

constexpr int CH   = 128;      // CH_IN == CH_LAT == CLASSES
constexpr int WW   = 131072;   // W
constexpr int NB   = 4;        // B
constexpr int NPIX = NB * WW;  // 524288
constexpr int TPB  = 256;

// ws float layout:
constexpr int OFF_W1T = 0;        // w1t[c][o], 128*128
constexpr int OFF_BNA = 16384;    // BN scale, 128
constexpr int OFF_BNC = 16512;    // BN offset (b1 folded), 128
constexpr int OFF_W2G = 16640;    // w2 grouped [rg][c][j8]: w2g[rg*1024 + c*8 + j] = w2[(rg*8+j)*128 + c]
constexpr int OFF_WM  = 33024;    // w2 row 128 (mask row), 128

__global__ __launch_bounds__(256) void prep_kernel(
    const float* __restrict__ w1, const float* __restrict__ b1,
    const float* __restrict__ gamma, const float* __restrict__ beta,
    const float* __restrict__ mean, const float* __restrict__ var,
    const float* __restrict__ w2,
    float* __restrict__ ws)
{
    const int tid = threadIdx.x;
    for (int i = tid; i < CH * CH; i += 256) {
        const int c = i >> 7, o = i & 127;
        ws[OFF_W1T + c * CH + o] = w1[o * CH + c];
    }
    if (tid < CH) {
        const float s = gamma[tid] / sqrtf(var[tid] + 1e-5f);  // identical math to R1-R3
        ws[OFF_BNA + tid] = s;
        ws[OFF_BNC + tid] = (b1[tid] - mean[tid]) * s + beta[tid];
        ws[OFF_WM  + tid] = w2[CH * CH + tid];
    }
    for (int i = tid; i < 16 * CH * 8; i += 256) {
        const int rg = i >> 10, r = i & 1023, c = r >> 3, j = r & 7;
        ws[OFF_W2G + i] = w2[(rg * 8 + j) * CH + c];
    }
}

// Fully fused, LDS-free, scratch-free:
//  - weights/BN/bias via wave-uniform s_loads (SGPR operand of v_fmac)
//  - acc[128] static-indexed everywhere (GEMM2 c-loop FULLY unrolled)
//  - GEMM2 in 16 row-groups of 8 static y-regs; mask row separate
__global__ __launch_bounds__(TPB, 2) void fused_kernel(
    const float* __restrict__ x,     // (B,128,1,W)
    const float* __restrict__ b2,    // (129)
    const float* __restrict__ cmw,   // (128,128)
    const float* __restrict__ cmb,   // (128)
    const float* __restrict__ ws,
    float* __restrict__ out)         // [0,NPIX): reg-out, [NPIX,2NPIX): mask
{
    const int tid = threadIdx.x;
    const int p   = blockIdx.x * TPB + tid;
    const int b   = p >> 17;                  // / W (uniform per block)
    const int w   = p & (WW - 1);

    const float* __restrict__ w1t = ws + OFF_W1T;
    const float* __restrict__ bnA = ws + OFF_BNA;
    const float* __restrict__ bnC = ws + OFF_BNC;
    const float* __restrict__ w2g = ws + OFF_W2G;
    const float* __restrict__ wm  = ws + OFF_WM;

    // ---- GEMM1: acc[o] = sum_c x[b,c,w] * w1[o][c]  (chain order == R1-R3) ----
    float acc[CH];
    #pragma unroll
    for (int o = 0; o < CH; ++o) acc[o] = 0.f;

    const float* xc = x + ((size_t)b * CH) * WW + w;
    #pragma unroll 4
    for (int c = 0; c < CH; ++c) {
        const float xv = xc[(size_t)c * WW];           // coalesced, 1 load/lane/c
        const float* __restrict__ wr = w1t + c * CH;   // wave-uniform -> s_load
        #pragma unroll
        for (int o = 0; o < CH; ++o)
            acc[o] = fmaf(xv, wr[o], acc[o]);          // static acc index
    }

    // ---- BN + LeakyReLU (b1 folded), in registers ----
    #pragma unroll
    for (int o = 0; o < CH; ++o) {
        const float v = fmaf(acc[o], bnA[o], bnC[o]);
        acc[o] = (v >= 0.f) ? v : 0.01f * v;
    }

    // ---- GEMM2 rows 0..127: 16 groups of 8, c FULLY unrolled (static acc[c]) ----
    float best = -3.0e38f;
    int   bidx = 0;
    #pragma unroll 1
    for (int rg = 0; rg < 16; ++rg) {
        float y[8];
        #pragma unroll
        for (int j = 0; j < 8; ++j) y[j] = b2[rg * 8 + j];        // uniform s_load
        const float* __restrict__ wg = w2g + rg * (CH * 8);
        #pragma unroll
        for (int c = 0; c < CH; ++c) {
            #pragma unroll
            for (int j = 0; j < 8; ++j)
                y[j] = fmaf(acc[c], wg[c * 8 + j], y[j]);         // s_load_dwordx8 per c
        }
        #pragma unroll
        for (int j = 0; j < 8; ++j) {
            const bool g = y[j] > best;                           // strict >, ascending
            best = g ? y[j] : best;
            bidx = g ? rg * 8 + j : bidx;
        }
    }

    // ---- mask row (w2 row 128): single chain, init b2[128], c ascending ----
    {
        float m = b2[CH];
        #pragma unroll
        for (int c = 0; c < CH; ++c)
            m = fmaf(acc[c], wm[c], m);
        out[NPIX + p] = (m >= 0.f) ? m : 0.01f * m;
    }

    // ---- cm gather (per-lane, L2) + reg dot: 4-way split as in R1-R3 ----
    {
        const float4* __restrict__ cr = (const float4*)(cmw + (size_t)bidx * CH);
        float r0 = 0.f, r1 = 0.f, r2 = 0.f, r3 = 0.f;
        #pragma unroll
        for (int c4 = 0; c4 < 32; ++c4) {
            const float4 v = cr[c4];
            r0 = fmaf(acc[c4*4+0], v.x, r0);
            r1 = fmaf(acc[c4*4+1], v.y, r1);
            r2 = fmaf(acc[c4*4+2], v.z, r2);
            r3 = fmaf(acc[c4*4+3], v.w, r3);
        }
        const float reg = ((r0 + r1) + (r2 + r3)) + cmb[bidx];
        out[p] = ((float)bidx + reg) * (1.0f / 128.0f);
    }
}

extern "C" void kernel_launch(void* const* d_in, const int* in_sizes, int n_in,
                              void* d_out, int out_size, void* d_ws, size_t ws_size,
                              hipStream_t stream) {
    const float* x     = (const float*)d_in[0];
    const float* w1    = (const float*)d_in[1];
    const float* b1    = (const float*)d_in[2];
    const float* gamma = (const float*)d_in[3];
    const float* beta  = (const float*)d_in[4];
    const float* mean  = (const float*)d_in[5];
    const float* var   = (const float*)d_in[6];
    const float* w2    = (const float*)d_in[7];
    const float* b2    = (const float*)d_in[8];
    const float* cmw   = (const float*)d_in[9];
    const float* cmb   = (const float*)d_in[10];
    float* ws  = (float*)d_ws;
    float* out = (float*)d_out;

    hipLaunchKernelGGL(prep_kernel, dim3(1), dim3(256), 0, stream,
                       w1, b1, gamma, beta, mean, var, w2, ws);
    hipLaunchKernelGGL(fused_kernel, dim3(NPIX / TPB), dim3(TPB), 0, stream,
                       x, b2, cmw, cmb, ws, out);
}